// Round 18
// baseline (58866.400 us; speedup 1.0000x reference)
//
#include <hip/hip_runtime.h>

#define DEV __device__ __forceinline__

constexpr int Bb = 64, Tt = 512, Ii = 256, Hd = 512;
constexpr int NWG = 1024, NTHR = 256;         // 4 WGs per CU (column-split, 8-row jobs)
constexpr int BbHd = Bb * Hd, BbIi = Bb * Ii;
constexpr int BbXA = Bb * 2048;               // gate-X preact slab

// 8 independent groups × 128 WGs × 8 batch rows. WG wg: g = wg>>7, j = wg&127.
// XCD(wg) = wg%8 = j%8. XCD-AFFINE COLUMN MAP (r17 fix): slot s -> column block
// cb = (s&7)*nper + (s>>3), so all slots on one XCD cover a CONTIGUOUS 64-col
// range of each weight matrix -> full 128B line use -> per-XCD weight set 1.6MB
// (L2-resident). Co-resident WGs (wg+256k) share j -> L1 reuse.
// Phases (~65.5k FMA/slot): A = gates-H K=512 (4×32, NC=16) + XA add;
// B = z/r K=1024 (128, NC=8); C = H-tilde 32 | gate-X(t+1) 64 | Ah 16 | X-mix 16.

// ---- workspace layout (floats) ----
// [0,16384): sync — per-group: counter @ uint g*64, gen flag @ uint g*64+32
constexpr int OFF_G  = 16384;                 // gates σ'd [4][64][512]
constexpr int OFF_F  = OFF_G + 4 * BbHd;      // F0 = z σ'd; F1 = R·H
constexpr int OFF_HB = OFF_F + 2 * BbHd;      // H double buffer [2][64][512]
constexpr int OFF_XB = OFF_HB + 2 * BbHd;     // X-mixed ring [2][64][256]
constexpr int OFF_AH = OFF_XB + 2 * BbIi;     // Ah preact ring [2][64][512]
constexpr int OFF_XA = OFF_AH + 2 * BbHd;     // gate-X preact ring [2][64][2048]
// end = 638976 floats = 2.56 MB

#define SMEM_BYTES 34816                      // staging [8][1088] (K=1024 skewed); red aliases

struct P {
  const float *tt, *mark;
  const float *Wxz_t, *Wxr_t, *Wxz_m, *Wxr_m, *Wxh;
  const float *Whz_t, *Whr_t, *Whz_m, *Whr_m, *Whh;
  const float *bz_t, *br_t, *bz_m, *br_m, *bh;
  const float *fWrt, *fWrm, *fWzt, *fWzm, *fWxt, *fWxm;
  const float *frb, *fzb, *fxb;
  float* out; float* ws;
};

enum { JA = 0, JB = 1, JRH = 2, JX = 3, JXB = 4, JX2 = 5 };

DEV float sig1(float x) { return 1.f / (1.f + __expf(-x)); }
DEV float tanh1(float x) { return 2.f * sig1(2.f * x) - 1.f; }
DEV float4 ld4(const float* p) { return *(const float4*)p; }
DEV int skw(int k) { return k + (k >> 4); }   // bank skew; blocks of 16 stay contiguous
DEV int xmap(int s, int nper) { return (s & 7) * nper + (s >> 3); }  // XCD-affine cb

// coherent (agent-scope) 8B load/store
DEV float2 ld2v(const float* p) {
  unsigned long long u = __hip_atomic_load((const unsigned long long*)p,
                                           __ATOMIC_RELAXED, __HIP_MEMORY_SCOPE_AGENT);
  return __builtin_bit_cast(float2, u);
}
DEV void st2v(float* p, float2 v) {
  __hip_atomic_store((unsigned long long*)p, __builtin_bit_cast(unsigned long long, v),
                     __ATOMIC_RELAXED, __HIP_MEMORY_SCOPE_AGENT);
}
DEV float4 ld4v(const float* p) {
  float2 a = ld2v(p), b = ld2v(p + 2);
  return make_float4(a.x, a.y, b.x, b.y);
}

// A-operand: 4 consecutive k. b = absolute row.
template<int TYPE>
DEV float4 loadA4(const P& p, int t, const float* aux, int side, int b, int k) {
  const float* ws = p.ws;
  if constexpr (TYPE == JA) {          // H(t-1), K=512
    return ld4v(ws + OFF_HB + ((t - 1) & 1) * BbHd + b * Hd + k);
  } else if constexpr (TYPE == JB) {   // [Zt|Zm] (side0) / [Rt|Rm] (side1)
    const int g = (k < Hd) ? side : side + 2;
    const int j = (k < Hd) ? k : k - Hd;
    return ld4v(ws + OFF_G + g * BbHd + b * Hd + j);
  } else if constexpr (TYPE == JRH) {  // R·H (512)
    return ld4v(ws + OFF_F + BbHd + b * Hd + k);
  } else if constexpr (TYPE == JX) {   // [Xt_raw | Xm_raw] row t
    if (k < Ii) return ld4(&p.tt[(b * Tt + t) * Ii + k]);
    return ld4(&p.mark[(b * Tt + t) * Ii + (k - Ii)]);
  } else if constexpr (TYPE == JXB) {  // X_mixed(t+1) ring (256)
    return ld4v(ws + OFF_XB + ((t + 1) & 1) * BbIi + b * Ii + k);
  } else {                             // JX2: raw input row t (256)
    return ld4(&aux[(b * Tt + t) * Ii + k]);
  }
}

// Full-K GEMM: out tile [8 rows x NC cols] at (rb, n0). A staged once to LDS (skewed);
// weights streamed from XCD-local L2; CPT cols per thread; S = NTHR*CPT/NC k-stripes;
// LDS reduce. Thread tid owns output elems e=2*tid (valid when e < 8*NC).
template<int TYPE, int K, int KSPL, int NC, int CPT>
DEV float2 job8(const P& p, float* lds, int t, const float* aux, int side, int rb,
                int n0, const float* wA, int sA, const float* wB, int sB) {
  const int tid = threadIdx.x;
  constexpr int KS = K + (K >> 4);     // skewed row stride
  constexpr int Kq = K / 4;
  for (int idx = tid; idx < 8 * Kq; idx += NTHR) {
    const int r = idx / Kq, i4 = (idx - r * Kq) * 4;
    float4 v = loadA4<TYPE>(p, t, aux, side, rb + r, i4);
    *(float4*)&lds[r * KS + skw(i4)] = v;
  }
  __syncthreads();
  constexpr int TPS = NC / CPT;        // threads per k-stripe
  constexpr int S = NTHR / TPS;        // k-stripes
  constexpr int Kper = K / S;
  const int kk = tid / TPS, cq = tid % TPS;
  const int c0 = n0 + CPT * cq;
  const int kbase = kk * Kper;
  float acc[8][CPT] = {};
  #pragma unroll 2
  for (int i = 0; i < Kper / 2; ++i) {
    const int k = kbase + 2 * i;
    const float* wr0 = (k < KSPL) ? &wA[k * sA] : &wB[(k - KSPL) * sB];
    const float* wr1 = (k + 1 < KSPL) ? &wA[(k + 1) * sA] : &wB[(k + 1 - KSPL) * sB];
    float w0[CPT], w1[CPT];
    if constexpr (CPT == 4) {
      float4 u0 = ld4(&wr0[c0]); w0[0]=u0.x; w0[1]=u0.y; w0[2]=u0.z; w0[3]=u0.w;
      float4 u1 = ld4(&wr1[c0]); w1[0]=u1.x; w1[1]=u1.y; w1[2]=u1.z; w1[3]=u1.w;
    } else {
      float2 u0 = *(const float2*)&wr0[c0]; w0[0]=u0.x; w0[1]=u0.y;
      float2 u1 = *(const float2*)&wr1[c0]; w1[0]=u1.x; w1[1]=u1.y;
    }
    #pragma unroll
    for (int r = 0; r < 8; ++r) {
      float2 a = *(const float2*)&lds[r * KS + skw(k)];
      #pragma unroll
      for (int c = 0; c < CPT; ++c)
        acc[r][c] = fmaf(a.y, w1[c], fmaf(a.x, w0[c], acc[r][c]));
    }
  }
  __syncthreads();
  float* red = lds;                    // [S][8*NC] floats, aliases staging
  #pragma unroll
  for (int r = 0; r < 8; ++r) {
    if constexpr (CPT == 4) {
      *(float4*)&red[(kk * 8 + r) * NC + CPT * cq] =
          make_float4(acc[r][0], acc[r][1], acc[r][2], acc[r][3]);
    } else {
      *(float2*)&red[(kk * 8 + r) * NC + CPT * cq] = make_float2(acc[r][0], acc[r][1]);
    }
  }
  __syncthreads();
  float2 s = make_float2(0.f, 0.f);
  const int e = tid * 2;
  if (e < 8 * NC) {
    #pragma unroll
    for (int q = 0; q < S; ++q) {
      float2 v = *(const float2*)&red[q * 8 * NC + e];
      s.x += v.x; s.y += v.y;
    }
  }
  return s;
}

// group barrier: 128 WGs, monotonic target
DEV void grpbar(float* ws, int g, unsigned tgt) {
  __syncthreads();
  if (threadIdx.x == 0) {
    asm volatile("s_waitcnt vmcnt(0)" ::: "memory");
    unsigned* cnt = (unsigned*)ws + g * 64;
    unsigned* gen = (unsigned*)ws + g * 64 + 32;
    unsigned a = __hip_atomic_fetch_add(cnt, 1u, __ATOMIC_RELAXED, __HIP_MEMORY_SCOPE_AGENT);
    if (a == 128u * tgt - 1u)
      __hip_atomic_store(gen, tgt, __ATOMIC_RELAXED, __HIP_MEMORY_SCOPE_AGENT);
    while (__hip_atomic_load(gen, __ATOMIC_RELAXED, __HIP_MEMORY_SCOPE_AGENT) < tgt)
      __builtin_amdgcn_s_sleep(1);
  }
  __syncthreads();
}

__global__ void ggru_init(float* ws) {
  const int i = blockIdx.x * 256 + threadIdx.x;
  if (i < 16384) ws[i] = 0.f;                       // sync region
  const int j = i - 16384;
  if (j >= 0 && j < BbHd) ws[OFF_HB + j] = 0.f;     // H0 = 0 (buffer 0)
}

__global__ __launch_bounds__(NTHR)
void ggru_persist(P p) {
  extern __shared__ float sm[];
  const int wg = blockIdx.x, tid = threadIdx.x;
  const int g = wg >> 7, j = wg & 127, rb = g * 8;  // group, slot, batch-row base
  float* ws = p.ws;
  unsigned bt = 0;
  const int e = tid * 2;

  // ---------- prologue P0: gate-X(1) 64 | X-mix(1) 16 | X-mix(2) 16 ----------
  if (j < 64) {            // gate-X(1): rows 0 -> XA[1]
    const int gate = j >> 4, s_ = j & 15, n0 = xmap(s_, 2) * 32;
    const float* wx = gate==0 ? p.Wxz_t : gate==1 ? p.Wxr_t : gate==2 ? p.Wxz_m : p.Wxr_m;
    const float* xin = (gate < 2) ? p.tt : p.mark;
    float2 s = job8<JX2, 256, 256, 32, 4>(p, sm, 0, xin, 0, rb, n0, wx, Hd, wx, Hd);
    if (tid < 128) {
      const int r = e >> 5, c = e & 31, col = n0 + c;
      st2v(ws + OFF_XA + 1 * BbXA + (rb + r) * 2048 + gate * 512 + col, s);
    }
  } else if (j < 96) {     // X-mix(1) (rows 0 -> XB[1]) and X-mix(2) (rows 1 -> XB[0])
    const int inst = (j - 64) >> 4, s_ = (j - 64) & 15, n0 = xmap(s_, 2) * 16;
    const int tp = inst;   // 0 or 1
    float2 s = job8<JX, 512, 256, 16, 2>(p, sm, tp, nullptr, 0, rb, n0, p.fWxt, Ii, p.fWxm, Ii);
    if (tid < 64) {
      const int r = e >> 4, c = e & 15, col = n0 + c, brow = rb + r;
      float2 bv = *(const float2*)&p.fxb[col];
      float g0 = sig1(s.x + bv.x), g1 = sig1(s.y + bv.y);
      float2 xt = *(const float2*)&p.tt[(brow * Tt + tp) * Ii + col];
      float2 xm = *(const float2*)&p.mark[(brow * Tt + tp) * Ii + col];
      st2v(ws + OFF_XB + ((tp + 1) & 1) * BbIi + brow * Ii + col,
           make_float2(g0 * xt.x + (1.f - g0) * xm.x, g1 * xt.y + (1.f - g1) * xm.y));
    }
  }
  grpbar(ws, g, ++bt);
  // ---------- prologue P1: Ah(1) (reads XB[1]) ----------
  if (j < 16) {
    const int n0 = xmap(j, 2) * 32;
    float2 s = job8<JXB, 256, 256, 32, 4>(p, sm, 0, nullptr, 0, rb, n0, p.Wxh, Hd, p.Wxh, Hd);
    if (tid < 128) {
      const int r = e >> 5, c = e & 31, col = n0 + c;
      st2v(ws + OFF_AH + 1 * BbHd + (rb + r) * Hd + col, s);
    }
  }
  grpbar(ws, g, ++bt);

  for (int t = 1; t <= Tt; ++t) {
    // ---------- phase A: gates-H K=512 (4 gates × 32 slots, NC=16) + XA -> σ -> G ----------
    {
      const int gate = j >> 5, s_ = j & 31, n0 = xmap(s_, 4) * 16;
      const float* wh = gate==0 ? p.Whz_t : gate==1 ? p.Whr_t : gate==2 ? p.Whz_m : p.Whr_m;
      float2 s = job8<JA, 512, 512, 16, 2>(p, sm, t, nullptr, 0, rb, n0, wh, Hd, wh, Hd);
      if (tid < 64) {
        const int r = e >> 4, c = e & 15, col = n0 + c;
        float2 xa = ld2v(ws + OFF_XA + (t & 1) * BbXA + (rb + r) * 2048 + gate * 512 + col);
        const float* bias = gate==0 ? p.bz_t : gate==1 ? p.br_t : gate==2 ? p.bz_m : p.br_m;
        float2 bv = *(const float2*)&bias[col];
        st2v(ws + OFF_G + gate * BbHd + (rb + r) * Hd + col,
             make_float2(sig1(s.x + xa.x + bv.x), sig1(s.y + xa.y + bv.y)));
      }
    }
    grpbar(ws, g, ++bt);
    // ---------- phase B: z/r K=1024, 128 slots (NC=8, CPT=2) ----------
    {
      const int side = j >> 6, s_ = j & 63, n0 = xmap(s_, 8) * 8;
      const float* wa = side ? p.fWrt : p.fWzt;
      const float* wb = side ? p.fWrm : p.fWzm;
      float2 s = job8<JB, 1024, 512, 8, 2>(p, sm, t, nullptr, side, rb, n0, wa, Hd, wb, Hd);
      if (tid < 32) {
        const int r = e >> 3, c = e & 7, col = n0 + c;
        const int base = (rb + r) * Hd + col;
        const float* bias = side ? p.frb : p.fzb;
        float2 bv = *(const float2*)&bias[col];
        float2 gg = make_float2(sig1(s.x + bv.x), sig1(s.y + bv.y));
        if (side == 0) {
          st2v(ws + OFF_F + base, gg);               // z
        } else {                                     // r -> R·H
          float2 rt = ld2v(ws + OFF_G + 1 * BbHd + base);
          float2 rm = ld2v(ws + OFF_G + 3 * BbHd + base);
          float2 ho = ld2v(ws + OFF_HB + ((t - 1) & 1) * BbHd + base);
          st2v(ws + OFF_F + BbHd + base,
               make_float2((gg.x * rt.x + (1.f - gg.x) * rm.x) * ho.x,
                           (gg.y * rt.y + (1.f - gg.y) * rm.y) * ho.y));
        }
      }
    }
    grpbar(ws, g, ++bt);
    // ---------- phase C: H-tilde 32 | gate-X(t+1) 64 | Ah(t+1) 16 | X-mix(t+2) 16 ----------
    if (j < 32) {          // H-tilde + epilogue, NC=16
      const int n0 = xmap(j, 4) * 16;
      float2 s = job8<JRH, 512, 512, 16, 2>(p, sm, t, nullptr, 0, rb, n0, p.Whh, Hd, p.Whh, Hd);
      if (tid < 64) {
        const int r = e >> 4, c = e & 15, col = n0 + c, brow = rb + r;
        const int base = brow * Hd + col;
        float2 ah = ld2v(ws + OFF_AH + (t & 1) * BbHd + base);
        float2 bv = *(const float2*)&p.bh[col];
        float ht0 = tanh1(s.x + ah.x + bv.x), ht1 = tanh1(s.y + ah.y + bv.y);
        float2 zf = ld2v(ws + OFF_F + base);
        float2 zt = ld2v(ws + OFF_G + base);
        float2 zm = ld2v(ws + OFF_G + 2 * BbHd + base);
        float2 ho = ld2v(ws + OFF_HB + ((t - 1) & 1) * BbHd + base);
        float Z0 = zf.x * zt.x + (1.f - zf.x) * zm.x;
        float Z1 = zf.y * zt.y + (1.f - zf.y) * zm.y;
        float2 hn = make_float2(Z0 * ho.x + (1.f - Z0) * ht0, Z1 * ho.y + (1.f - Z1) * ht1);
        st2v(ws + OFF_HB + (t & 1) * BbHd + base, hn);
        *(float2*)&p.out[(brow * Tt + (t - 1)) * Hd + col] = hn;
        if (t == Tt) *(float2*)&p.out[Bb * Tt * Hd + brow * Hd + col] = hn;
      }
    } else if (j < 96) {   // gate-X(t+1): rows t -> XA[(t+1)&1]
      if (t < Tt) {
        const int jj = j - 32, gate = jj >> 4, s_ = jj & 15, n0 = xmap(s_, 2) * 32;
        const float* wx = gate==0 ? p.Wxz_t : gate==1 ? p.Wxr_t : gate==2 ? p.Wxz_m : p.Wxr_m;
        const float* xin = (gate < 2) ? p.tt : p.mark;
        float2 s = job8<JX2, 256, 256, 32, 4>(p, sm, t, xin, 0, rb, n0, wx, Hd, wx, Hd);
        if (tid < 128) {
          const int r = e >> 5, c = e & 31, col = n0 + c;
          st2v(ws + OFF_XA + ((t + 1) & 1) * BbXA + (rb + r) * 2048 + gate * 512 + col, s);
        }
      }
    } else if (j < 112) {  // Ah(t+1): reads XB[(t+1)&1] -> AH[(t+1)&1]
      if (t < Tt) {
        const int jj = j - 96, n0 = xmap(jj, 2) * 32;
        float2 s = job8<JXB, 256, 256, 32, 4>(p, sm, t, nullptr, 0, rb, n0, p.Wxh, Hd, p.Wxh, Hd);
        if (tid < 128) {
          const int r = e >> 5, c = e & 31, col = n0 + c;
          st2v(ws + OFF_AH + ((t + 1) & 1) * BbHd + (rb + r) * Hd + col, s);
        }
      }
    } else {               // X-mix(t+2): rows t+1 -> XB[(t+2)&1]
      if (t + 1 < Tt) {
        const int jj = j - 112, n0 = xmap(jj, 2) * 16;
        const int tp = t + 1;
        float2 s = job8<JX, 512, 256, 16, 2>(p, sm, tp, nullptr, 0, rb, n0, p.fWxt, Ii, p.fWxm, Ii);
        if (tid < 64) {
          const int r = e >> 4, c = e & 15, col = n0 + c, brow = rb + r;
          float2 bv = *(const float2*)&p.fxb[col];
          float g0 = sig1(s.x + bv.x), g1 = sig1(s.y + bv.y);
          float2 xt = *(const float2*)&p.tt[(brow * Tt + tp) * Ii + col];
          float2 xm = *(const float2*)&p.mark[(brow * Tt + tp) * Ii + col];
          st2v(ws + OFF_XB + ((tp + 1) & 1) * BbIi + brow * Ii + col,
               make_float2(g0 * xt.x + (1.f - g0) * xm.x, g1 * xt.y + (1.f - g1) * xm.y));
        }
      }
    }
    grpbar(ws, g, ++bt);
  }
}

extern "C" void kernel_launch(void* const* d_in, const int* in_sizes, int n_in,
                              void* d_out, int out_size, void* d_ws, size_t ws_size,
                              hipStream_t stream) {
  P pr;
  pr.tt    = (const float*)d_in[0];
  pr.mark  = (const float*)d_in[1];
  pr.Wxz_t = (const float*)d_in[2];
  pr.Wxr_t = (const float*)d_in[3];
  pr.Wxz_m = (const float*)d_in[4];
  pr.Wxr_m = (const float*)d_in[5];
  pr.Wxh   = (const float*)d_in[6];
  pr.Whz_t = (const float*)d_in[7];
  pr.Whr_t = (const float*)d_in[8];
  pr.Whz_m = (const float*)d_in[9];
  pr.Whr_m = (const float*)d_in[10];
  pr.Whh   = (const float*)d_in[11];
  pr.bz_t  = (const float*)d_in[12];
  pr.br_t  = (const float*)d_in[13];
  pr.bz_m  = (const float*)d_in[14];
  pr.br_m  = (const float*)d_in[15];
  pr.bh    = (const float*)d_in[16];
  pr.fWrt  = (const float*)d_in[17];
  pr.fWrm  = (const float*)d_in[18];
  pr.fWzt  = (const float*)d_in[19];
  pr.fWzm  = (const float*)d_in[20];
  pr.fWxt  = (const float*)d_in[21];
  pr.fWxm  = (const float*)d_in[22];
  pr.frb   = (const float*)d_in[23];
  pr.fzb   = (const float*)d_in[24];
  pr.fxb   = (const float*)d_in[25];
  pr.out = (float*)d_out;
  pr.ws  = (float*)d_ws;

  hipLaunchKernelGGL(ggru_init, dim3(192), dim3(256), 0, stream, (float*)d_ws);

  void* args[] = { (void*)&pr };
  hipError_t err = hipLaunchCooperativeKernel((const void*)ggru_persist,
                                              dim3(NWG), dim3(NTHR),
                                              args, (unsigned)SMEM_BYTES, stream);
  if (err != hipSuccess) {
    hipLaunchKernelGGL(ggru_persist, dim3(NWG), dim3(NTHR), SMEM_BYTES, stream, pr);
  }
}

// Round 19
// 28105.914 us; speedup vs baseline: 2.0944x; 2.0944x over previous
//
#include <hip/hip_runtime.h>

#define DEV __device__ __forceinline__

constexpr int Bb = 64, Tt = 512, Ii = 256, Hd = 512;
constexpr int NWG = 512, NTHR = 256;          // 2 WGs per CU (coop grids >512 WGs serialize!)
constexpr int BbHd = Bb * Hd, BbIi = Bb * Ii;
constexpr int BbXA = Bb * 2048;               // gate-X preact slab

// 8 independent groups × 64 WGs × 8 batch rows. WG wg: g = wg>>6, j = wg&63.
// Phases balanced at ~131k FMA/slot: A = gates-H K=512 (64 slots NC=32 CPT=4) + XA;
// B = z/r K=1024 (64 slots NC=16 CPT=4, S=64); C = gate-X(t+1) 32 | H-tilde 16 |
// Ah(t+1) 8 | X-mix(t+2) 8.  LDS staging skewed (k + (k>>4)) against bank conflicts.

// ---- workspace layout (floats) ----
// [0,16384): sync — per-group: counter @ uint g*64, gen flag @ uint g*64+32
constexpr int OFF_G  = 16384;                 // gates σ'd [4][64][512]
constexpr int OFF_F  = OFF_G + 4 * BbHd;      // F0 = z σ'd; F1 = R·H
constexpr int OFF_HB = OFF_F + 2 * BbHd;      // H double buffer [2][64][512]
constexpr int OFF_XB = OFF_HB + 2 * BbHd;     // X-mixed ring [2][64][256]
constexpr int OFF_AH = OFF_XB + 2 * BbIi;     // Ah preact ring [2][64][512]
constexpr int OFF_XA = OFF_AH + 2 * BbHd;     // gate-X preact ring [2][64][2048]
// end = 638976 floats = 2.56 MB

#define SMEM_BYTES 34816                      // staging [8][1088] (K=1024 skewed); red aliases

struct P {
  const float *tt, *mark;
  const float *Wxz_t, *Wxr_t, *Wxz_m, *Wxr_m, *Wxh;
  const float *Whz_t, *Whr_t, *Whz_m, *Whr_m, *Whh;
  const float *bz_t, *br_t, *bz_m, *br_m, *bh;
  const float *fWrt, *fWrm, *fWzt, *fWzm, *fWxt, *fWxm;
  const float *frb, *fzb, *fxb;
  float* out; float* ws;
};

enum { JA = 0, JB = 1, JRH = 2, JX = 3, JXB = 4, JX2 = 5 };

DEV float sig1(float x) { return 1.f / (1.f + __expf(-x)); }
DEV float tanh1(float x) { return 2.f * sig1(2.f * x) - 1.f; }
DEV float4 ld4(const float* p) { return *(const float4*)p; }
DEV int skw(int k) { return k + (k >> 4); }   // bank skew; blocks of 16 stay contiguous

// coherent (agent-scope) 8B load/store
DEV float2 ld2v(const float* p) {
  unsigned long long u = __hip_atomic_load((const unsigned long long*)p,
                                           __ATOMIC_RELAXED, __HIP_MEMORY_SCOPE_AGENT);
  return __builtin_bit_cast(float2, u);
}
DEV void st2v(float* p, float2 v) {
  __hip_atomic_store((unsigned long long*)p, __builtin_bit_cast(unsigned long long, v),
                     __ATOMIC_RELAXED, __HIP_MEMORY_SCOPE_AGENT);
}
DEV float4 ld4v(const float* p) {
  float2 a = ld2v(p), b = ld2v(p + 2);
  return make_float4(a.x, a.y, b.x, b.y);
}

// A-operand: 4 consecutive k. b = absolute row.
template<int TYPE>
DEV float4 loadA4(const P& p, int t, const float* aux, int side, int b, int k) {
  const float* ws = p.ws;
  if constexpr (TYPE == JA) {          // H(t-1), K=512
    return ld4v(ws + OFF_HB + ((t - 1) & 1) * BbHd + b * Hd + k);
  } else if constexpr (TYPE == JB) {   // [Zt|Zm] (side0) / [Rt|Rm] (side1)
    const int g = (k < Hd) ? side : side + 2;
    const int j = (k < Hd) ? k : k - Hd;
    return ld4v(ws + OFF_G + g * BbHd + b * Hd + j);
  } else if constexpr (TYPE == JRH) {  // R·H (512)
    return ld4v(ws + OFF_F + BbHd + b * Hd + k);
  } else if constexpr (TYPE == JX) {   // [Xt_raw | Xm_raw] row t
    if (k < Ii) return ld4(&p.tt[(b * Tt + t) * Ii + k]);
    return ld4(&p.mark[(b * Tt + t) * Ii + (k - Ii)]);
  } else if constexpr (TYPE == JXB) {  // X_mixed(t+1) ring (256)
    return ld4v(ws + OFF_XB + ((t + 1) & 1) * BbIi + b * Ii + k);
  } else {                             // JX2: raw input row t (256)
    return ld4(&aux[(b * Tt + t) * Ii + k]);
  }
}

// Full-K GEMM: out tile [8 rows x NC cols] at (rb, n0). A staged once to LDS (skewed);
// weights streamed from XCD-local L2; CPT cols per thread; S = NTHR*CPT/NC k-stripes;
// LDS reduce. Thread tid owns output elems e=2*tid (valid when e < 8*NC).
template<int TYPE, int K, int KSPL, int NC, int CPT>
DEV float2 job8(const P& p, float* lds, int t, const float* aux, int side, int rb,
                int n0, const float* wA, int sA, const float* wB, int sB) {
  const int tid = threadIdx.x;
  constexpr int KS = K + (K >> 4);     // skewed row stride
  constexpr int Kq = K / 4;
  for (int idx = tid; idx < 8 * Kq; idx += NTHR) {
    const int r = idx / Kq, i4 = (idx - r * Kq) * 4;
    float4 v = loadA4<TYPE>(p, t, aux, side, rb + r, i4);
    *(float4*)&lds[r * KS + skw(i4)] = v;
  }
  __syncthreads();
  constexpr int TPS = NC / CPT;        // threads per k-stripe
  constexpr int S = NTHR / TPS;        // k-stripes
  constexpr int Kper = K / S;
  const int kk = tid / TPS, cq = tid % TPS;
  const int c0 = n0 + CPT * cq;
  const int kbase = kk * Kper;
  float acc[8][CPT] = {};
  #pragma unroll 2
  for (int i = 0; i < Kper / 2; ++i) {
    const int k = kbase + 2 * i;
    const float* wr0 = (k < KSPL) ? &wA[k * sA] : &wB[(k - KSPL) * sB];
    const float* wr1 = (k + 1 < KSPL) ? &wA[(k + 1) * sA] : &wB[(k + 1 - KSPL) * sB];
    float w0[CPT], w1[CPT];
    if constexpr (CPT == 4) {
      float4 u0 = ld4(&wr0[c0]); w0[0]=u0.x; w0[1]=u0.y; w0[2]=u0.z; w0[3]=u0.w;
      float4 u1 = ld4(&wr1[c0]); w1[0]=u1.x; w1[1]=u1.y; w1[2]=u1.z; w1[3]=u1.w;
    } else {
      float2 u0 = *(const float2*)&wr0[c0]; w0[0]=u0.x; w0[1]=u0.y;
      float2 u1 = *(const float2*)&wr1[c0]; w1[0]=u1.x; w1[1]=u1.y;
    }
    #pragma unroll
    for (int r = 0; r < 8; ++r) {
      float2 a = *(const float2*)&lds[r * KS + skw(k)];
      #pragma unroll
      for (int c = 0; c < CPT; ++c)
        acc[r][c] = fmaf(a.y, w1[c], fmaf(a.x, w0[c], acc[r][c]));
    }
  }
  __syncthreads();
  float* red = lds;                    // [S][8*NC] <= 8192 floats, aliases staging
  #pragma unroll
  for (int r = 0; r < 8; ++r) {
    if constexpr (CPT == 4) {
      *(float4*)&red[(kk * 8 + r) * NC + CPT * cq] =
          make_float4(acc[r][0], acc[r][1], acc[r][2], acc[r][3]);
    } else {
      *(float2*)&red[(kk * 8 + r) * NC + CPT * cq] = make_float2(acc[r][0], acc[r][1]);
    }
  }
  __syncthreads();
  float2 s = make_float2(0.f, 0.f);
  const int e = tid * 2;
  if (e < 8 * NC) {
    #pragma unroll 8
    for (int q = 0; q < S; ++q) {
      float2 v = *(const float2*)&red[q * 8 * NC + e];
      s.x += v.x; s.y += v.y;
    }
  }
  return s;
}

// group barrier: 64 WGs, monotonic target
DEV void grpbar(float* ws, int g, unsigned tgt) {
  __syncthreads();
  if (threadIdx.x == 0) {
    asm volatile("s_waitcnt vmcnt(0)" ::: "memory");
    unsigned* cnt = (unsigned*)ws + g * 64;
    unsigned* gen = (unsigned*)ws + g * 64 + 32;
    unsigned a = __hip_atomic_fetch_add(cnt, 1u, __ATOMIC_RELAXED, __HIP_MEMORY_SCOPE_AGENT);
    if (a == 64u * tgt - 1u)
      __hip_atomic_store(gen, tgt, __ATOMIC_RELAXED, __HIP_MEMORY_SCOPE_AGENT);
    while (__hip_atomic_load(gen, __ATOMIC_RELAXED, __HIP_MEMORY_SCOPE_AGENT) < tgt)
      __builtin_amdgcn_s_sleep(1);
  }
  __syncthreads();
}

__global__ void ggru_init(float* ws) {
  const int i = blockIdx.x * 256 + threadIdx.x;
  if (i < 16384) ws[i] = 0.f;                       // sync region
  const int j = i - 16384;
  if (j >= 0 && j < BbHd) ws[OFF_HB + j] = 0.f;     // H0 = 0 (buffer 0)
}

__global__ __launch_bounds__(NTHR)
void ggru_persist(P p) {
  extern __shared__ float sm[];
  const int wg = blockIdx.x, tid = threadIdx.x;
  const int g = wg >> 6, j = wg & 63, rb = g * 8;   // group, slot, batch-row base
  float* ws = p.ws;
  unsigned bt = 0;
  const int e = tid * 2;

  // ---------- prologue P0: gate-X(1) | X-mix(1) | X-mix(2) ----------
  if (j < 32) {            // gate-X(1): rows 0 -> XA[1]
    const int gate = j >> 3, cb = j & 7, n0 = cb * 64;
    const float* wx = gate==0 ? p.Wxz_t : gate==1 ? p.Wxr_t : gate==2 ? p.Wxz_m : p.Wxr_m;
    const float* xin = (gate < 2) ? p.tt : p.mark;
    float2 s = job8<JX2, 256, 256, 64, 4>(p, sm, 0, xin, 0, rb, n0, wx, Hd, wx, Hd);
    const int r = e >> 6, c = e & 63, col = n0 + c;
    st2v(ws + OFF_XA + 1 * BbXA + (rb + r) * 2048 + gate * 512 + col, s);
  } else if (j < 48) {     // X-mix(1) (rows 0 -> XB[1]) and X-mix(2) (rows 1 -> XB[0])
    const int inst = (j - 32) >> 3, jj = (j - 32) & 7, n0 = jj * 32;
    const int tp = inst;   // 0 or 1
    float2 s = job8<JX, 512, 256, 32, 4>(p, sm, tp, nullptr, 0, rb, n0, p.fWxt, Ii, p.fWxm, Ii);
    if (tid < 128) {
      const int r = e >> 5, c = e & 31, col = n0 + c, brow = rb + r;
      float2 bv = *(const float2*)&p.fxb[col];
      float g0 = sig1(s.x + bv.x), g1 = sig1(s.y + bv.y);
      float2 xt = *(const float2*)&p.tt[(brow * Tt + tp) * Ii + col];
      float2 xm = *(const float2*)&p.mark[(brow * Tt + tp) * Ii + col];
      st2v(ws + OFF_XB + ((tp + 1) & 1) * BbIi + brow * Ii + col,
           make_float2(g0 * xt.x + (1.f - g0) * xm.x, g1 * xt.y + (1.f - g1) * xm.y));
    }
  }
  grpbar(ws, g, ++bt);
  // ---------- prologue P1: Ah(1) (reads XB[1]) ----------
  if (j < 8) {
    const int n0 = j * 64;
    float2 s = job8<JXB, 256, 256, 64, 4>(p, sm, 0, nullptr, 0, rb, n0, p.Wxh, Hd, p.Wxh, Hd);
    const int r = e >> 6, c = e & 63, col = n0 + c;
    st2v(ws + OFF_AH + 1 * BbHd + (rb + r) * Hd + col, s);
  }
  grpbar(ws, g, ++bt);

  for (int t = 1; t <= Tt; ++t) {
    // ---------- phase A: gates-H K=512 (64 slots NC=32) + XA + bias -> σ -> G ----------
    {
      const int gate = j >> 4, cb = j & 15, n0 = cb * 32;
      const float* wh = gate==0 ? p.Whz_t : gate==1 ? p.Whr_t : gate==2 ? p.Whz_m : p.Whr_m;
      float2 s = job8<JA, 512, 512, 32, 4>(p, sm, t, nullptr, 0, rb, n0, wh, Hd, wh, Hd);
      if (tid < 128) {
        const int r = e >> 5, c = e & 31, col = n0 + c;
        float2 xa = ld2v(ws + OFF_XA + (t & 1) * BbXA + (rb + r) * 2048 + gate * 512 + col);
        const float* bias = gate==0 ? p.bz_t : gate==1 ? p.br_t : gate==2 ? p.bz_m : p.br_m;
        float2 bv = *(const float2*)&bias[col];
        st2v(ws + OFF_G + gate * BbHd + (rb + r) * Hd + col,
             make_float2(sig1(s.x + xa.x + bv.x), sig1(s.y + xa.y + bv.y)));
      }
    }
    grpbar(ws, g, ++bt);
    // ---------- phase B: z/r K=1024, 64 slots (NC=16, CPT=4, S=64) ----------
    {
      const int side = j >> 5, n0 = (j & 31) * 16;
      const float* wa = side ? p.fWrt : p.fWzt;
      const float* wb = side ? p.fWrm : p.fWzm;
      float2 s = job8<JB, 1024, 512, 16, 4>(p, sm, t, nullptr, side, rb, n0, wa, Hd, wb, Hd);
      if (tid < 64) {
        const int r = e >> 4, c = e & 15, col = n0 + c;
        const int base = (rb + r) * Hd + col;
        const float* bias = side ? p.frb : p.fzb;
        float2 bv = *(const float2*)&bias[col];
        float2 gg = make_float2(sig1(s.x + bv.x), sig1(s.y + bv.y));
        if (side == 0) {
          st2v(ws + OFF_F + base, gg);               // z
        } else {                                     // r -> R·H
          float2 rt = ld2v(ws + OFF_G + 1 * BbHd + base);
          float2 rm = ld2v(ws + OFF_G + 3 * BbHd + base);
          float2 ho = ld2v(ws + OFF_HB + ((t - 1) & 1) * BbHd + base);
          st2v(ws + OFF_F + BbHd + base,
               make_float2((gg.x * rt.x + (1.f - gg.x) * rm.x) * ho.x,
                           (gg.y * rt.y + (1.f - gg.y) * rm.y) * ho.y));
        }
      }
    }
    grpbar(ws, g, ++bt);
    // ---------- phase C: gate-X(t+1) 32 | H-tilde 16 | Ah(t+1) 8 | X-mix(t+2) 8 ----------
    if (j < 32) {
      if (t < Tt) {        // gate-X(t+1): rows t -> XA[(t+1)&1]
        const int gate = j >> 3, cb = j & 7, n0 = cb * 64;
        const float* wx = gate==0 ? p.Wxz_t : gate==1 ? p.Wxr_t : gate==2 ? p.Wxz_m : p.Wxr_m;
        const float* xin = (gate < 2) ? p.tt : p.mark;
        float2 s = job8<JX2, 256, 256, 64, 4>(p, sm, t, xin, 0, rb, n0, wx, Hd, wx, Hd);
        const int r = e >> 6, c = e & 63, col = n0 + c;
        st2v(ws + OFF_XA + ((t + 1) & 1) * BbXA + (rb + r) * 2048 + gate * 512 + col, s);
      }
    } else if (j < 48) {   // H-tilde + epilogue
      const int jj = j - 32, n0 = jj * 32;
      float2 s = job8<JRH, 512, 512, 32, 4>(p, sm, t, nullptr, 0, rb, n0, p.Whh, Hd, p.Whh, Hd);
      if (tid < 128) {
        const int r = e >> 5, c = e & 31, col = n0 + c, brow = rb + r;
        const int base = brow * Hd + col;
        float2 ah = ld2v(ws + OFF_AH + (t & 1) * BbHd + base);
        float2 bv = *(const float2*)&p.bh[col];
        float ht0 = tanh1(s.x + ah.x + bv.x), ht1 = tanh1(s.y + ah.y + bv.y);
        float2 zf = ld2v(ws + OFF_F + base);
        float2 zt = ld2v(ws + OFF_G + base);
        float2 zm = ld2v(ws + OFF_G + 2 * BbHd + base);
        float2 ho = ld2v(ws + OFF_HB + ((t - 1) & 1) * BbHd + base);
        float Z0 = zf.x * zt.x + (1.f - zf.x) * zm.x;
        float Z1 = zf.y * zt.y + (1.f - zf.y) * zm.y;
        float2 hn = make_float2(Z0 * ho.x + (1.f - Z0) * ht0, Z1 * ho.y + (1.f - Z1) * ht1);
        st2v(ws + OFF_HB + (t & 1) * BbHd + base, hn);
        *(float2*)&p.out[(brow * Tt + (t - 1)) * Hd + col] = hn;
        if (t == Tt) *(float2*)&p.out[Bb * Tt * Hd + brow * Hd + col] = hn;
      }
    } else if (j < 56) {   // Ah(t+1): reads XB[(t+1)&1] -> AH[(t+1)&1]
      if (t < Tt) {
        const int jj = j - 48, n0 = jj * 64;
        float2 s = job8<JXB, 256, 256, 64, 4>(p, sm, t, nullptr, 0, rb, n0, p.Wxh, Hd, p.Wxh, Hd);
        const int r = e >> 6, c = e & 63, col = n0 + c;
        st2v(ws + OFF_AH + ((t + 1) & 1) * BbHd + (rb + r) * Hd + col, s);
      }
    } else {               // X-mix(t+2): rows t+1 -> XB[(t+2)&1]
      if (t + 1 < Tt) {
        const int jj = j - 56, n0 = jj * 32;
        const int tp = t + 1;
        float2 s = job8<JX, 512, 256, 32, 4>(p, sm, tp, nullptr, 0, rb, n0, p.fWxt, Ii, p.fWxm, Ii);
        if (tid < 128) {
          const int r = e >> 5, c = e & 31, col = n0 + c, brow = rb + r;
          float2 bv = *(const float2*)&p.fxb[col];
          float g0 = sig1(s.x + bv.x), g1 = sig1(s.y + bv.y);
          float2 xt = *(const float2*)&p.tt[(brow * Tt + tp) * Ii + col];
          float2 xm = *(const float2*)&p.mark[(brow * Tt + tp) * Ii + col];
          st2v(ws + OFF_XB + ((tp + 1) & 1) * BbIi + brow * Ii + col,
               make_float2(g0 * xt.x + (1.f - g0) * xm.x, g1 * xt.y + (1.f - g1) * xm.y));
        }
      }
    }
    grpbar(ws, g, ++bt);
  }
}

extern "C" void kernel_launch(void* const* d_in, const int* in_sizes, int n_in,
                              void* d_out, int out_size, void* d_ws, size_t ws_size,
                              hipStream_t stream) {
  P pr;
  pr.tt    = (const float*)d_in[0];
  pr.mark  = (const float*)d_in[1];
  pr.Wxz_t = (const float*)d_in[2];
  pr.Wxr_t = (const float*)d_in[3];
  pr.Wxz_m = (const float*)d_in[4];
  pr.Wxr_m = (const float*)d_in[5];
  pr.Wxh   = (const float*)d_in[6];
  pr.Whz_t = (const float*)d_in[7];
  pr.Whr_t = (const float*)d_in[8];
  pr.Whz_m = (const float*)d_in[9];
  pr.Whr_m = (const float*)d_in[10];
  pr.Whh   = (const float*)d_in[11];
  pr.bz_t  = (const float*)d_in[12];
  pr.br_t  = (const float*)d_in[13];
  pr.bz_m  = (const float*)d_in[14];
  pr.br_m  = (const float*)d_in[15];
  pr.bh    = (const float*)d_in[16];
  pr.fWrt  = (const float*)d_in[17];
  pr.fWrm  = (const float*)d_in[18];
  pr.fWzt  = (const float*)d_in[19];
  pr.fWzm  = (const float*)d_in[20];
  pr.fWxt  = (const float*)d_in[21];
  pr.fWxm  = (const float*)d_in[22];
  pr.frb   = (const float*)d_in[23];
  pr.fzb   = (const float*)d_in[24];
  pr.fxb   = (const float*)d_in[25];
  pr.out = (float*)d_out;
  pr.ws  = (float*)d_ws;

  hipLaunchKernelGGL(ggru_init, dim3(192), dim3(256), 0, stream, (float*)d_ws);

  void* args[] = { (void*)&pr };
  hipError_t err = hipLaunchCooperativeKernel((const void*)ggru_persist,
                                              dim3(NWG), dim3(NTHR),
                                              args, (unsigned)SMEM_BYTES, stream);
  if (err != hipSuccess) {
    hipLaunchKernelGGL(ggru_persist, dim3(NWG), dim3(NTHR), SMEM_BYTES, stream, pr);
  }
}

// Round 20
// 10620.243 us; speedup vs baseline: 5.5428x; 2.6464x over previous
//
#include <hip/hip_runtime.h>

#define DEV __device__ __forceinline__

constexpr int Bb = 64, Tt = 512, Ii = 256, Hd = 512;
constexpr int NWG = 512, NTHR = 256;          // 2 WGs per CU (coop grids >512 WGs serialize!)
constexpr int BbHd = Bb * Hd, BbIi = Bb * Ii;
constexpr int BbXA = Bb * 2048;               // gate-X preact slab

// 8 independent groups × 64 WGs × 8 batch rows. WG wg: g = wg>>6, j = wg&63.
// Phases balanced at ~131k FMA/slot: A = gates-H K=512 (64 slots NC=32 CPT=4) + XA;
// B = z/r K=1024 (64 slots NC=16 CPT=2); C = gate-X(t+1) 32 | H-tilde 16 |
// Ah(t+1) 8 | X-mix(t+2) 8.
// LDS staging uses ALIGNMENT-PRESERVING block skew: skw4(k) = k + ((k>>4)<<2)
// (16B pad per 16-float block). float4/float2 alignment preserved; k-stripe
// starts (Kper=16 -> stride 20 floats) spread across 8 distinct banks.

// ---- workspace layout (floats) ----
// [0,16384): sync — per-group: counter @ uint g*64, gen flag @ uint g*64+32
constexpr int OFF_G  = 16384;                 // gates σ'd [4][64][512]
constexpr int OFF_F  = OFF_G + 4 * BbHd;      // F0 = z σ'd; F1 = R·H
constexpr int OFF_HB = OFF_F + 2 * BbHd;      // H double buffer [2][64][512]
constexpr int OFF_XB = OFF_HB + 2 * BbHd;     // X-mixed ring [2][64][256]
constexpr int OFF_AH = OFF_XB + 2 * BbIi;     // Ah preact ring [2][64][512]
constexpr int OFF_XA = OFF_AH + 2 * BbHd;     // gate-X preact ring [2][64][2048]
// end = 638976 floats = 2.56 MB

#define SMEM_BYTES 40960                      // staging [8][1280] (K=1024 skewed); red aliases

struct P {
  const float *tt, *mark;
  const float *Wxz_t, *Wxr_t, *Wxz_m, *Wxr_m, *Wxh;
  const float *Whz_t, *Whr_t, *Whz_m, *Whr_m, *Whh;
  const float *bz_t, *br_t, *bz_m, *br_m, *bh;
  const float *fWrt, *fWrm, *fWzt, *fWzm, *fWxt, *fWxm;
  const float *frb, *fzb, *fxb;
  float* out; float* ws;
};

enum { JA = 0, JB = 1, JRH = 2, JX = 3, JXB = 4, JX2 = 5 };

DEV float sig1(float x) { return 1.f / (1.f + __expf(-x)); }
DEV float tanh1(float x) { return 2.f * sig1(2.f * x) - 1.f; }
DEV float4 ld4(const float* p) { return *(const float4*)p; }
DEV int skw4(int k) { return k + ((k >> 4) << 2); }  // 16B pad per 16-float block

// coherent (agent-scope) 8B load/store
DEV float2 ld2v(const float* p) {
  unsigned long long u = __hip_atomic_load((const unsigned long long*)p,
                                           __ATOMIC_RELAXED, __HIP_MEMORY_SCOPE_AGENT);
  return __builtin_bit_cast(float2, u);
}
DEV void st2v(float* p, float2 v) {
  __hip_atomic_store((unsigned long long*)p, __builtin_bit_cast(unsigned long long, v),
                     __ATOMIC_RELAXED, __HIP_MEMORY_SCOPE_AGENT);
}
DEV float4 ld4v(const float* p) {
  float2 a = ld2v(p), b = ld2v(p + 2);
  return make_float4(a.x, a.y, b.x, b.y);
}

// A-operand: 4 consecutive k. b = absolute row.
template<int TYPE>
DEV float4 loadA4(const P& p, int t, const float* aux, int side, int b, int k) {
  const float* ws = p.ws;
  if constexpr (TYPE == JA) {          // H(t-1), K=512
    return ld4v(ws + OFF_HB + ((t - 1) & 1) * BbHd + b * Hd + k);
  } else if constexpr (TYPE == JB) {   // [Zt|Zm] (side0) / [Rt|Rm] (side1)
    const int g = (k < Hd) ? side : side + 2;
    const int j = (k < Hd) ? k : k - Hd;
    return ld4v(ws + OFF_G + g * BbHd + b * Hd + j);
  } else if constexpr (TYPE == JRH) {  // R·H (512)
    return ld4v(ws + OFF_F + BbHd + b * Hd + k);
  } else if constexpr (TYPE == JX) {   // [Xt_raw | Xm_raw] row t
    if (k < Ii) return ld4(&p.tt[(b * Tt + t) * Ii + k]);
    return ld4(&p.mark[(b * Tt + t) * Ii + (k - Ii)]);
  } else if constexpr (TYPE == JXB) {  // X_mixed(t+1) ring (256)
    return ld4v(ws + OFF_XB + ((t + 1) & 1) * BbIi + b * Ii + k);
  } else {                             // JX2: raw input row t (256)
    return ld4(&aux[(b * Tt + t) * Ii + k]);
  }
}

// Full-K GEMM: out tile [8 rows x NC cols] at (rb, n0). A staged once to LDS
// (block-skewed, alignment preserved); weights streamed from XCD-local L2; CPT
// cols/thread; S = NTHR*CPT/NC k-stripes; LDS reduce. Thread tid owns output
// elems e=2*tid (valid when e < 8*NC).
template<int TYPE, int K, int KSPL, int NC, int CPT>
DEV float2 job8(const P& p, float* lds, int t, const float* aux, int side, int rb,
                int n0, const float* wA, int sA, const float* wB, int sB) {
  const int tid = threadIdx.x;
  constexpr int KS = K + (K >> 2);     // skewed row stride (5K/4)
  constexpr int Kq = K / 4;
  for (int idx = tid; idx < 8 * Kq; idx += NTHR) {
    const int r = idx / Kq, i4 = (idx - r * Kq) * 4;
    float4 v = loadA4<TYPE>(p, t, aux, side, rb + r, i4);
    *(float4*)&lds[r * KS + skw4(i4)] = v;
  }
  __syncthreads();
  constexpr int TPS = NC / CPT;        // threads per k-stripe
  constexpr int S = NTHR / TPS;        // k-stripes
  constexpr int Kper = K / S;
  const int kk = tid / TPS, cq = tid % TPS;
  const int c0 = n0 + CPT * cq;
  const int kbase = kk * Kper;
  float acc[8][CPT] = {};
  #pragma unroll 2
  for (int i = 0; i < Kper / 2; ++i) {
    const int k = kbase + 2 * i;
    const float* wr0 = (k < KSPL) ? &wA[k * sA] : &wB[(k - KSPL) * sB];
    const float* wr1 = (k + 1 < KSPL) ? &wA[(k + 1) * sA] : &wB[(k + 1 - KSPL) * sB];
    float w0[CPT], w1[CPT];
    if constexpr (CPT == 4) {
      float4 u0 = ld4(&wr0[c0]); w0[0]=u0.x; w0[1]=u0.y; w0[2]=u0.z; w0[3]=u0.w;
      float4 u1 = ld4(&wr1[c0]); w1[0]=u1.x; w1[1]=u1.y; w1[2]=u1.z; w1[3]=u1.w;
    } else {
      float2 u0 = *(const float2*)&wr0[c0]; w0[0]=u0.x; w0[1]=u0.y;
      float2 u1 = *(const float2*)&wr1[c0]; w1[0]=u1.x; w1[1]=u1.y;
    }
    #pragma unroll
    for (int r = 0; r < 8; ++r) {
      float2 a = *(const float2*)&lds[r * KS + skw4(k)];
      #pragma unroll
      for (int c = 0; c < CPT; ++c)
        acc[r][c] = fmaf(a.y, w1[c], fmaf(a.x, w0[c], acc[r][c]));
    }
  }
  __syncthreads();
  float* red = lds;                    // [S][8*NC] floats, aliases staging
  #pragma unroll
  for (int r = 0; r < 8; ++r) {
    if constexpr (CPT == 4) {
      *(float4*)&red[(kk * 8 + r) * NC + CPT * cq] =
          make_float4(acc[r][0], acc[r][1], acc[r][2], acc[r][3]);
    } else {
      *(float2*)&red[(kk * 8 + r) * NC + CPT * cq] = make_float2(acc[r][0], acc[r][1]);
    }
  }
  __syncthreads();
  float2 s = make_float2(0.f, 0.f);
  const int e = tid * 2;
  if (e < 8 * NC) {
    #pragma unroll
    for (int q = 0; q < S; ++q) {
      float2 v = *(const float2*)&red[q * 8 * NC + e];
      s.x += v.x; s.y += v.y;
    }
  }
  return s;
}

// group barrier: 64 WGs, monotonic target
DEV void grpbar(float* ws, int g, unsigned tgt) {
  __syncthreads();
  if (threadIdx.x == 0) {
    asm volatile("s_waitcnt vmcnt(0)" ::: "memory");
    unsigned* cnt = (unsigned*)ws + g * 64;
    unsigned* gen = (unsigned*)ws + g * 64 + 32;
    unsigned a = __hip_atomic_fetch_add(cnt, 1u, __ATOMIC_RELAXED, __HIP_MEMORY_SCOPE_AGENT);
    if (a == 64u * tgt - 1u)
      __hip_atomic_store(gen, tgt, __ATOMIC_RELAXED, __HIP_MEMORY_SCOPE_AGENT);
    while (__hip_atomic_load(gen, __ATOMIC_RELAXED, __HIP_MEMORY_SCOPE_AGENT) < tgt)
      __builtin_amdgcn_s_sleep(1);
  }
  __syncthreads();
}

__global__ void ggru_init(float* ws) {
  const int i = blockIdx.x * 256 + threadIdx.x;
  if (i < 16384) ws[i] = 0.f;                       // sync region
  const int j = i - 16384;
  if (j >= 0 && j < BbHd) ws[OFF_HB + j] = 0.f;     // H0 = 0 (buffer 0)
}

__global__ __launch_bounds__(NTHR)
void ggru_persist(P p) {
  extern __shared__ float sm[];
  const int wg = blockIdx.x, tid = threadIdx.x;
  const int g = wg >> 6, j = wg & 63, rb = g * 8;   // group, slot, batch-row base
  float* ws = p.ws;
  unsigned bt = 0;
  const int e = tid * 2;

  // ---------- prologue P0: gate-X(1) | X-mix(1) | X-mix(2) ----------
  if (j < 32) {            // gate-X(1): rows 0 -> XA[1]
    const int gate = j >> 3, cb = j & 7, n0 = cb * 64;
    const float* wx = gate==0 ? p.Wxz_t : gate==1 ? p.Wxr_t : gate==2 ? p.Wxz_m : p.Wxr_m;
    const float* xin = (gate < 2) ? p.tt : p.mark;
    float2 s = job8<JX2, 256, 256, 64, 4>(p, sm, 0, xin, 0, rb, n0, wx, Hd, wx, Hd);
    const int r = e >> 6, c = e & 63, col = n0 + c;
    st2v(ws + OFF_XA + 1 * BbXA + (rb + r) * 2048 + gate * 512 + col, s);
  } else if (j < 48) {     // X-mix(1) (rows 0 -> XB[1]) and X-mix(2) (rows 1 -> XB[0])
    const int inst = (j - 32) >> 3, jj = (j - 32) & 7, n0 = jj * 32;
    const int tp = inst;   // 0 or 1
    float2 s = job8<JX, 512, 256, 32, 4>(p, sm, tp, nullptr, 0, rb, n0, p.fWxt, Ii, p.fWxm, Ii);
    if (tid < 128) {
      const int r = e >> 5, c = e & 31, col = n0 + c, brow = rb + r;
      float2 bv = *(const float2*)&p.fxb[col];
      float g0 = sig1(s.x + bv.x), g1 = sig1(s.y + bv.y);
      float2 xt = *(const float2*)&p.tt[(brow * Tt + tp) * Ii + col];
      float2 xm = *(const float2*)&p.mark[(brow * Tt + tp) * Ii + col];
      st2v(ws + OFF_XB + ((tp + 1) & 1) * BbIi + brow * Ii + col,
           make_float2(g0 * xt.x + (1.f - g0) * xm.x, g1 * xt.y + (1.f - g1) * xm.y));
    }
  }
  grpbar(ws, g, ++bt);
  // ---------- prologue P1: Ah(1) (reads XB[1]) ----------
  if (j < 8) {
    const int n0 = j * 64;
    float2 s = job8<JXB, 256, 256, 64, 4>(p, sm, 0, nullptr, 0, rb, n0, p.Wxh, Hd, p.Wxh, Hd);
    const int r = e >> 6, c = e & 63, col = n0 + c;
    st2v(ws + OFF_AH + 1 * BbHd + (rb + r) * Hd + col, s);
  }
  grpbar(ws, g, ++bt);

  for (int t = 1; t <= Tt; ++t) {
    // ---------- phase A: gates-H K=512 (64 slots NC=32) + XA + bias -> σ -> G ----------
    {
      const int gate = j >> 4, cb = j & 15, n0 = cb * 32;
      const float* wh = gate==0 ? p.Whz_t : gate==1 ? p.Whr_t : gate==2 ? p.Whz_m : p.Whr_m;
      float2 s = job8<JA, 512, 512, 32, 4>(p, sm, t, nullptr, 0, rb, n0, wh, Hd, wh, Hd);
      if (tid < 128) {
        const int r = e >> 5, c = e & 31, col = n0 + c;
        float2 xa = ld2v(ws + OFF_XA + (t & 1) * BbXA + (rb + r) * 2048 + gate * 512 + col);
        const float* bias = gate==0 ? p.bz_t : gate==1 ? p.br_t : gate==2 ? p.bz_m : p.br_m;
        float2 bv = *(const float2*)&bias[col];
        st2v(ws + OFF_G + gate * BbHd + (rb + r) * Hd + col,
             make_float2(sig1(s.x + xa.x + bv.x), sig1(s.y + xa.y + bv.y)));
      }
    }
    grpbar(ws, g, ++bt);
    // ---------- phase B: z/r K=1024, 64 slots (NC=16, CPT=2) ----------
    {
      const int side = j >> 5, n0 = (j & 31) * 16;
      const float* wa = side ? p.fWrt : p.fWzt;
      const float* wb = side ? p.fWrm : p.fWzm;
      float2 s = job8<JB, 1024, 512, 16, 2>(p, sm, t, nullptr, side, rb, n0, wa, Hd, wb, Hd);
      if (tid < 64) {
        const int r = e >> 4, c = e & 15, col = n0 + c;
        const int base = (rb + r) * Hd + col;
        const float* bias = side ? p.frb : p.fzb;
        float2 bv = *(const float2*)&bias[col];
        float2 gg = make_float2(sig1(s.x + bv.x), sig1(s.y + bv.y));
        if (side == 0) {
          st2v(ws + OFF_F + base, gg);               // z
        } else {                                     // r -> R·H
          float2 rt = ld2v(ws + OFF_G + 1 * BbHd + base);
          float2 rm = ld2v(ws + OFF_G + 3 * BbHd + base);
          float2 ho = ld2v(ws + OFF_HB + ((t - 1) & 1) * BbHd + base);
          st2v(ws + OFF_F + BbHd + base,
               make_float2((gg.x * rt.x + (1.f - gg.x) * rm.x) * ho.x,
                           (gg.y * rt.y + (1.f - gg.y) * rm.y) * ho.y));
        }
      }
    }
    grpbar(ws, g, ++bt);
    // ---------- phase C: gate-X(t+1) 32 | H-tilde 16 | Ah(t+1) 8 | X-mix(t+2) 8 ----------
    if (j < 32) {
      if (t < Tt) {        // gate-X(t+1): rows t -> XA[(t+1)&1]
        const int gate = j >> 3, cb = j & 7, n0 = cb * 64;
        const float* wx = gate==0 ? p.Wxz_t : gate==1 ? p.Wxr_t : gate==2 ? p.Wxz_m : p.Wxr_m;
        const float* xin = (gate < 2) ? p.tt : p.mark;
        float2 s = job8<JX2, 256, 256, 64, 4>(p, sm, t, xin, 0, rb, n0, wx, Hd, wx, Hd);
        const int r = e >> 6, c = e & 63, col = n0 + c;
        st2v(ws + OFF_XA + ((t + 1) & 1) * BbXA + (rb + r) * 2048 + gate * 512 + col, s);
      }
    } else if (j < 48) {   // H-tilde + epilogue
      const int jj = j - 32, n0 = jj * 32;
      float2 s = job8<JRH, 512, 512, 32, 4>(p, sm, t, nullptr, 0, rb, n0, p.Whh, Hd, p.Whh, Hd);
      if (tid < 128) {
        const int r = e >> 5, c = e & 31, col = n0 + c, brow = rb + r;
        const int base = brow * Hd + col;
        float2 ah = ld2v(ws + OFF_AH + (t & 1) * BbHd + base);
        float2 bv = *(const float2*)&p.bh[col];
        float ht0 = tanh1(s.x + ah.x + bv.x), ht1 = tanh1(s.y + ah.y + bv.y);
        float2 zf = ld2v(ws + OFF_F + base);
        float2 zt = ld2v(ws + OFF_G + base);
        float2 zm = ld2v(ws + OFF_G + 2 * BbHd + base);
        float2 ho = ld2v(ws + OFF_HB + ((t - 1) & 1) * BbHd + base);
        float Z0 = zf.x * zt.x + (1.f - zf.x) * zm.x;
        float Z1 = zf.y * zt.y + (1.f - zf.y) * zm.y;
        float2 hn = make_float2(Z0 * ho.x + (1.f - Z0) * ht0, Z1 * ho.y + (1.f - Z1) * ht1);
        st2v(ws + OFF_HB + (t & 1) * BbHd + base, hn);
        *(float2*)&p.out[(brow * Tt + (t - 1)) * Hd + col] = hn;
        if (t == Tt) *(float2*)&p.out[Bb * Tt * Hd + brow * Hd + col] = hn;
      }
    } else if (j < 56) {   // Ah(t+1): reads XB[(t+1)&1] -> AH[(t+1)&1]
      if (t < Tt) {
        const int jj = j - 48, n0 = jj * 64;
        float2 s = job8<JXB, 256, 256, 64, 4>(p, sm, t, nullptr, 0, rb, n0, p.Wxh, Hd, p.Wxh, Hd);
        const int r = e >> 6, c = e & 63, col = n0 + c;
        st2v(ws + OFF_AH + ((t + 1) & 1) * BbHd + (rb + r) * Hd + col, s);
      }
    } else {               // X-mix(t+2): rows t+1 -> XB[(t+2)&1]
      if (t + 1 < Tt) {
        const int jj = j - 56, n0 = jj * 32;
        const int tp = t + 1;
        float2 s = job8<JX, 512, 256, 32, 4>(p, sm, tp, nullptr, 0, rb, n0, p.fWxt, Ii, p.fWxm, Ii);
        if (tid < 128) {
          const int r = e >> 5, c = e & 31, col = n0 + c, brow = rb + r;
          float2 bv = *(const float2*)&p.fxb[col];
          float g0 = sig1(s.x + bv.x), g1 = sig1(s.y + bv.y);
          float2 xt = *(const float2*)&p.tt[(brow * Tt + tp) * Ii + col];
          float2 xm = *(const float2*)&p.mark[(brow * Tt + tp) * Ii + col];
          st2v(ws + OFF_XB + ((tp + 1) & 1) * BbIi + brow * Ii + col,
               make_float2(g0 * xt.x + (1.f - g0) * xm.x, g1 * xt.y + (1.f - g1) * xm.y));
        }
      }
    }
    grpbar(ws, g, ++bt);
  }
}

extern "C" void kernel_launch(void* const* d_in, const int* in_sizes, int n_in,
                              void* d_out, int out_size, void* d_ws, size_t ws_size,
                              hipStream_t stream) {
  P pr;
  pr.tt    = (const float*)d_in[0];
  pr.mark  = (const float*)d_in[1];
  pr.Wxz_t = (const float*)d_in[2];
  pr.Wxr_t = (const float*)d_in[3];
  pr.Wxz_m = (const float*)d_in[4];
  pr.Wxr_m = (const float*)d_in[5];
  pr.Wxh   = (const float*)d_in[6];
  pr.Whz_t = (const float*)d_in[7];
  pr.Whr_t = (const float*)d_in[8];
  pr.Whz_m = (const float*)d_in[9];
  pr.Whr_m = (const float*)d_in[10];
  pr.Whh   = (const float*)d_in[11];
  pr.bz_t  = (const float*)d_in[12];
  pr.br_t  = (const float*)d_in[13];
  pr.bz_m  = (const float*)d_in[14];
  pr.br_m  = (const float*)d_in[15];
  pr.bh    = (const float*)d_in[16];
  pr.fWrt  = (const float*)d_in[17];
  pr.fWrm  = (const float*)d_in[18];
  pr.fWzt  = (const float*)d_in[19];
  pr.fWzm  = (const float*)d_in[20];
  pr.fWxt  = (const float*)d_in[21];
  pr.fWxm  = (const float*)d_in[22];
  pr.frb   = (const float*)d_in[23];
  pr.fzb   = (const float*)d_in[24];
  pr.fxb   = (const float*)d_in[25];
  pr.out = (float*)d_out;
  pr.ws  = (float*)d_ws;

  hipLaunchKernelGGL(ggru_init, dim3(192), dim3(256), 0, stream, (float*)d_ws);

  void* args[] = { (void*)&pr };
  hipError_t err = hipLaunchCooperativeKernel((const void*)ggru_persist,
                                              dim3(NWG), dim3(NTHR),
                                              args, (unsigned)SMEM_BYTES, stream);
  if (err != hipSuccess) {
    hipLaunchKernelGGL(ggru_persist, dim3(NWG), dim3(NTHR), SMEM_BYTES, stream, pr);
  }
}

// Round 21
// 10511.198 us; speedup vs baseline: 5.6004x; 1.0104x over previous
//
#include <hip/hip_runtime.h>

#define DEV __device__ __forceinline__

constexpr int Bb = 64, Tt = 512, Ii = 256, Hd = 512;
constexpr int NWG = 512, NTHR = 256;          // 2 WGs per CU (coop grids >512 WGs serialize!)
constexpr int BbHd = Bb * Hd, BbIi = Bb * Ii;
constexpr int BbXA = Bb * 2048;               // gate-X preact slab

// 8 independent groups × 64 WGs × 8 batch rows. WG wg: g = wg>>6, j = wg&63.
// Phases balanced at ~131k FMA/slot: A = gates-H K=512 (64 slots NC=32 CPT=4) + XA;
// B = z/r K=1024 (64 slots NC=16 CPT=2); C = gate-X(t+1) 32 | H-tilde 16 |
// Ah(t+1) 8 | X-mix(t+2) 8.
// LDS staging: alignment-preserving block skew skw4(k) = k + ((k>>4)<<2).
// Group barrier: 2-LEVEL TREE (8 leaves of 8 WGs @ j&7, root, per-leaf gen flags)
// -> 8 RMWs/line instead of 64; polls spread over 8 lines.

// ---- workspace layout (floats) ----
// [0,16384): sync — per-group region of 512 uints @ g*512:
//   leaf counters 8 @ stride 32, root @ uint 256, leaf gen flags 8 @ 288 + i*32
constexpr int OFF_G  = 16384;                 // gates σ'd [4][64][512]
constexpr int OFF_F  = OFF_G + 4 * BbHd;      // F0 = z σ'd; F1 = R·H
constexpr int OFF_HB = OFF_F + 2 * BbHd;      // H double buffer [2][64][512]
constexpr int OFF_XB = OFF_HB + 2 * BbHd;     // X-mixed ring [2][64][256]
constexpr int OFF_AH = OFF_XB + 2 * BbIi;     // Ah preact ring [2][64][512]
constexpr int OFF_XA = OFF_AH + 2 * BbHd;     // gate-X preact ring [2][64][2048]
// end = 638976 floats = 2.56 MB

#define SMEM_BYTES 40960                      // staging [8][1280] (K=1024 skewed); red aliases

struct P {
  const float *tt, *mark;
  const float *Wxz_t, *Wxr_t, *Wxz_m, *Wxr_m, *Wxh;
  const float *Whz_t, *Whr_t, *Whz_m, *Whr_m, *Whh;
  const float *bz_t, *br_t, *bz_m, *br_m, *bh;
  const float *fWrt, *fWrm, *fWzt, *fWzm, *fWxt, *fWxm;
  const float *frb, *fzb, *fxb;
  float* out; float* ws;
};

enum { JA = 0, JB = 1, JRH = 2, JX = 3, JXB = 4, JX2 = 5 };

DEV float sig1(float x) { return 1.f / (1.f + __expf(-x)); }
DEV float tanh1(float x) { return 2.f * sig1(2.f * x) - 1.f; }
DEV float4 ld4(const float* p) { return *(const float4*)p; }
DEV int skw4(int k) { return k + ((k >> 4) << 2); }  // 16B pad per 16-float block

// coherent (agent-scope) 8B load/store
DEV float2 ld2v(const float* p) {
  unsigned long long u = __hip_atomic_load((const unsigned long long*)p,
                                           __ATOMIC_RELAXED, __HIP_MEMORY_SCOPE_AGENT);
  return __builtin_bit_cast(float2, u);
}
DEV void st2v(float* p, float2 v) {
  __hip_atomic_store((unsigned long long*)p, __builtin_bit_cast(unsigned long long, v),
                     __ATOMIC_RELAXED, __HIP_MEMORY_SCOPE_AGENT);
}
DEV float4 ld4v(const float* p) {
  float2 a = ld2v(p), b = ld2v(p + 2);
  return make_float4(a.x, a.y, b.x, b.y);
}

// A-operand: 4 consecutive k. b = absolute row.
template<int TYPE>
DEV float4 loadA4(const P& p, int t, const float* aux, int side, int b, int k) {
  const float* ws = p.ws;
  if constexpr (TYPE == JA) {          // H(t-1), K=512
    return ld4v(ws + OFF_HB + ((t - 1) & 1) * BbHd + b * Hd + k);
  } else if constexpr (TYPE == JB) {   // [Zt|Zm] (side0) / [Rt|Rm] (side1)
    const int g = (k < Hd) ? side : side + 2;
    const int j = (k < Hd) ? k : k - Hd;
    return ld4v(ws + OFF_G + g * BbHd + b * Hd + j);
  } else if constexpr (TYPE == JRH) {  // R·H (512)
    return ld4v(ws + OFF_F + BbHd + b * Hd + k);
  } else if constexpr (TYPE == JX) {   // [Xt_raw | Xm_raw] row t
    if (k < Ii) return ld4(&p.tt[(b * Tt + t) * Ii + k]);
    return ld4(&p.mark[(b * Tt + t) * Ii + (k - Ii)]);
  } else if constexpr (TYPE == JXB) {  // X_mixed(t+1) ring (256)
    return ld4v(ws + OFF_XB + ((t + 1) & 1) * BbIi + b * Ii + k);
  } else {                             // JX2: raw input row t (256)
    return ld4(&aux[(b * Tt + t) * Ii + k]);
  }
}

// Full-K GEMM: out tile [8 rows x NC cols] at (rb, n0). A staged once to LDS
// (block-skewed, alignment preserved); weights streamed from XCD-local L2; CPT
// cols/thread; S = NTHR*CPT/NC k-stripes; LDS reduce. Thread tid owns output
// elems e=2*tid (valid when e < 8*NC).
template<int TYPE, int K, int KSPL, int NC, int CPT>
DEV float2 job8(const P& p, float* lds, int t, const float* aux, int side, int rb,
                int n0, const float* wA, int sA, const float* wB, int sB) {
  const int tid = threadIdx.x;
  constexpr int KS = K + (K >> 2);     // skewed row stride (5K/4)
  constexpr int Kq = K / 4;
  for (int idx = tid; idx < 8 * Kq; idx += NTHR) {
    const int r = idx / Kq, i4 = (idx - r * Kq) * 4;
    float4 v = loadA4<TYPE>(p, t, aux, side, rb + r, i4);
    *(float4*)&lds[r * KS + skw4(i4)] = v;
  }
  __syncthreads();
  constexpr int TPS = NC / CPT;        // threads per k-stripe
  constexpr int S = NTHR / TPS;        // k-stripes
  constexpr int Kper = K / S;
  const int kk = tid / TPS, cq = tid % TPS;
  const int c0 = n0 + CPT * cq;
  const int kbase = kk * Kper;
  float acc[8][CPT] = {};
  #pragma unroll 2
  for (int i = 0; i < Kper / 2; ++i) {
    const int k = kbase + 2 * i;
    const float* wr0 = (k < KSPL) ? &wA[k * sA] : &wB[(k - KSPL) * sB];
    const float* wr1 = (k + 1 < KSPL) ? &wA[(k + 1) * sA] : &wB[(k + 1 - KSPL) * sB];
    float w0[CPT], w1[CPT];
    if constexpr (CPT == 4) {
      float4 u0 = ld4(&wr0[c0]); w0[0]=u0.x; w0[1]=u0.y; w0[2]=u0.z; w0[3]=u0.w;
      float4 u1 = ld4(&wr1[c0]); w1[0]=u1.x; w1[1]=u1.y; w1[2]=u1.z; w1[3]=u1.w;
    } else {
      float2 u0 = *(const float2*)&wr0[c0]; w0[0]=u0.x; w0[1]=u0.y;
      float2 u1 = *(const float2*)&wr1[c0]; w1[0]=u1.x; w1[1]=u1.y;
    }
    #pragma unroll
    for (int r = 0; r < 8; ++r) {
      float2 a = *(const float2*)&lds[r * KS + skw4(k)];
      #pragma unroll
      for (int c = 0; c < CPT; ++c)
        acc[r][c] = fmaf(a.y, w1[c], fmaf(a.x, w0[c], acc[r][c]));
    }
  }
  __syncthreads();
  float* red = lds;                    // [S][8*NC] floats, aliases staging
  #pragma unroll
  for (int r = 0; r < 8; ++r) {
    if constexpr (CPT == 4) {
      *(float4*)&red[(kk * 8 + r) * NC + CPT * cq] =
          make_float4(acc[r][0], acc[r][1], acc[r][2], acc[r][3]);
    } else {
      *(float2*)&red[(kk * 8 + r) * NC + CPT * cq] = make_float2(acc[r][0], acc[r][1]);
    }
  }
  __syncthreads();
  float2 s = make_float2(0.f, 0.f);
  const int e = tid * 2;
  if (e < 8 * NC) {
    #pragma unroll
    for (int q = 0; q < S; ++q) {
      float2 v = *(const float2*)&red[q * 8 * NC + e];
      s.x += v.x; s.y += v.y;
    }
  }
  return s;
}

// 2-level group barrier: 8 leaves (j&7) of 8 WGs, root, per-leaf gen flags.
// Monotonic: leaf arrival a == 8*tgt-1 -> bump root; root r == 8*tgt-1 -> flags.
DEV void grpbar(float* ws, int g, int j, unsigned tgt) {
  __syncthreads();
  if (threadIdx.x == 0) {
    asm volatile("s_waitcnt vmcnt(0)" ::: "memory");
    unsigned* base = (unsigned*)ws + g * 512;
    unsigned* leaf = base + (j & 7) * 32;
    unsigned* root = base + 256;
    unsigned* lgen = base + 288 + (j & 7) * 32;   // wait: 288 + 7*32 = 512 > region!
    // region is 512 uints; flags at 288..288+7*32=512 would overflow by 32.
    // use stride 24 instead: flags at 288 + i*24, max 288+168+.. = 456+? -> safe 288+7*24=456
    lgen = base + 288 + (j & 7) * 24;
    unsigned a = __hip_atomic_fetch_add(leaf, 1u, __ATOMIC_RELAXED, __HIP_MEMORY_SCOPE_AGENT);
    if (a == 8u * tgt - 1u) {
      unsigned r = __hip_atomic_fetch_add(root, 1u, __ATOMIC_RELAXED, __HIP_MEMORY_SCOPE_AGENT);
      if (r == 8u * tgt - 1u) {
        #pragma unroll
        for (int i = 0; i < 8; ++i)
          __hip_atomic_store(base + 288 + i * 24, tgt, __ATOMIC_RELAXED, __HIP_MEMORY_SCOPE_AGENT);
      }
    }
    while (__hip_atomic_load(lgen, __ATOMIC_RELAXED, __HIP_MEMORY_SCOPE_AGENT) < tgt)
      __builtin_amdgcn_s_sleep(1);
  }
  __syncthreads();
}

__global__ void ggru_init(float* ws) {
  const int i = blockIdx.x * 256 + threadIdx.x;
  if (i < 16384) ws[i] = 0.f;                       // sync region
  const int j = i - 16384;
  if (j >= 0 && j < BbHd) ws[OFF_HB + j] = 0.f;     // H0 = 0 (buffer 0)
}

__global__ __launch_bounds__(NTHR)
void ggru_persist(P p) {
  extern __shared__ float sm[];
  const int wg = blockIdx.x, tid = threadIdx.x;
  const int g = wg >> 6, j = wg & 63, rb = g * 8;   // group, slot, batch-row base
  float* ws = p.ws;
  unsigned bt = 0;
  const int e = tid * 2;

  // ---------- prologue P0: gate-X(1) | X-mix(1) | X-mix(2) ----------
  if (j < 32) {            // gate-X(1): rows 0 -> XA[1]
    const int gate = j >> 3, cb = j & 7, n0 = cb * 64;
    const float* wx = gate==0 ? p.Wxz_t : gate==1 ? p.Wxr_t : gate==2 ? p.Wxz_m : p.Wxr_m;
    const float* xin = (gate < 2) ? p.tt : p.mark;
    float2 s = job8<JX2, 256, 256, 64, 4>(p, sm, 0, xin, 0, rb, n0, wx, Hd, wx, Hd);
    const int r = e >> 6, c = e & 63, col = n0 + c;
    st2v(ws + OFF_XA + 1 * BbXA + (rb + r) * 2048 + gate * 512 + col, s);
  } else if (j < 48) {     // X-mix(1) (rows 0 -> XB[1]) and X-mix(2) (rows 1 -> XB[0])
    const int inst = (j - 32) >> 3, jj = (j - 32) & 7, n0 = jj * 32;
    const int tp = inst;   // 0 or 1
    float2 s = job8<JX, 512, 256, 32, 4>(p, sm, tp, nullptr, 0, rb, n0, p.fWxt, Ii, p.fWxm, Ii);
    if (tid < 128) {
      const int r = e >> 5, c = e & 31, col = n0 + c, brow = rb + r;
      float2 bv = *(const float2*)&p.fxb[col];
      float g0 = sig1(s.x + bv.x), g1 = sig1(s.y + bv.y);
      float2 xt = *(const float2*)&p.tt[(brow * Tt + tp) * Ii + col];
      float2 xm = *(const float2*)&p.mark[(brow * Tt + tp) * Ii + col];
      st2v(ws + OFF_XB + ((tp + 1) & 1) * BbIi + brow * Ii + col,
           make_float2(g0 * xt.x + (1.f - g0) * xm.x, g1 * xt.y + (1.f - g1) * xm.y));
    }
  }
  grpbar(ws, g, j, ++bt);
  // ---------- prologue P1: Ah(1) (reads XB[1]) ----------
  if (j < 8) {
    const int n0 = j * 64;
    float2 s = job8<JXB, 256, 256, 64, 4>(p, sm, 0, nullptr, 0, rb, n0, p.Wxh, Hd, p.Wxh, Hd);
    const int r = e >> 6, c = e & 63, col = n0 + c;
    st2v(ws + OFF_AH + 1 * BbHd + (rb + r) * Hd + col, s);
  }
  grpbar(ws, g, j, ++bt);

  for (int t = 1; t <= Tt; ++t) {
    // ---------- phase A: gates-H K=512 (64 slots NC=32) + XA + bias -> σ -> G ----------
    {
      const int gate = j >> 4, cb = j & 15, n0 = cb * 32;
      const float* wh = gate==0 ? p.Whz_t : gate==1 ? p.Whr_t : gate==2 ? p.Whz_m : p.Whr_m;
      float2 s = job8<JA, 512, 512, 32, 4>(p, sm, t, nullptr, 0, rb, n0, wh, Hd, wh, Hd);
      if (tid < 128) {
        const int r = e >> 5, c = e & 31, col = n0 + c;
        float2 xa = ld2v(ws + OFF_XA + (t & 1) * BbXA + (rb + r) * 2048 + gate * 512 + col);
        const float* bias = gate==0 ? p.bz_t : gate==1 ? p.br_t : gate==2 ? p.bz_m : p.br_m;
        float2 bv = *(const float2*)&bias[col];
        st2v(ws + OFF_G + gate * BbHd + (rb + r) * Hd + col,
             make_float2(sig1(s.x + xa.x + bv.x), sig1(s.y + xa.y + bv.y)));
      }
    }
    grpbar(ws, g, j, ++bt);
    // ---------- phase B: z/r K=1024, 64 slots (NC=16, CPT=2) ----------
    {
      const int side = j >> 5, n0 = (j & 31) * 16;
      const float* wa = side ? p.fWrt : p.fWzt;
      const float* wb = side ? p.fWrm : p.fWzm;
      float2 s = job8<JB, 1024, 512, 16, 2>(p, sm, t, nullptr, side, rb, n0, wa, Hd, wb, Hd);
      if (tid < 64) {
        const int r = e >> 4, c = e & 15, col = n0 + c;
        const int base = (rb + r) * Hd + col;
        const float* bias = side ? p.frb : p.fzb;
        float2 bv = *(const float2*)&bias[col];
        float2 gg = make_float2(sig1(s.x + bv.x), sig1(s.y + bv.y));
        if (side == 0) {
          st2v(ws + OFF_F + base, gg);               // z
        } else {                                     // r -> R·H
          float2 rt = ld2v(ws + OFF_G + 1 * BbHd + base);
          float2 rm = ld2v(ws + OFF_G + 3 * BbHd + base);
          float2 ho = ld2v(ws + OFF_HB + ((t - 1) & 1) * BbHd + base);
          st2v(ws + OFF_F + BbHd + base,
               make_float2((gg.x * rt.x + (1.f - gg.x) * rm.x) * ho.x,
                           (gg.y * rt.y + (1.f - gg.y) * rm.y) * ho.y));
        }
      }
    }
    grpbar(ws, g, j, ++bt);
    // ---------- phase C: gate-X(t+1) 32 | H-tilde 16 | Ah(t+1) 8 | X-mix(t+2) 8 ----------
    if (j < 32) {
      if (t < Tt) {        // gate-X(t+1): rows t -> XA[(t+1)&1]
        const int gate = j >> 3, cb = j & 7, n0 = cb * 64;
        const float* wx = gate==0 ? p.Wxz_t : gate==1 ? p.Wxr_t : gate==2 ? p.Wxz_m : p.Wxr_m;
        const float* xin = (gate < 2) ? p.tt : p.mark;
        float2 s = job8<JX2, 256, 256, 64, 4>(p, sm, t, xin, 0, rb, n0, wx, Hd, wx, Hd);
        const int r = e >> 6, c = e & 63, col = n0 + c;
        st2v(ws + OFF_XA + ((t + 1) & 1) * BbXA + (rb + r) * 2048 + gate * 512 + col, s);
      }
    } else if (j < 48) {   // H-tilde + epilogue
      const int jj = j - 32, n0 = jj * 32;
      float2 s = job8<JRH, 512, 512, 32, 4>(p, sm, t, nullptr, 0, rb, n0, p.Whh, Hd, p.Whh, Hd);
      if (tid < 128) {
        const int r = e >> 5, c = e & 31, col = n0 + c, brow = rb + r;
        const int base = brow * Hd + col;
        float2 ah = ld2v(ws + OFF_AH + (t & 1) * BbHd + base);
        float2 bv = *(const float2*)&p.bh[col];
        float ht0 = tanh1(s.x + ah.x + bv.x), ht1 = tanh1(s.y + ah.y + bv.y);
        float2 zf = ld2v(ws + OFF_F + base);
        float2 zt = ld2v(ws + OFF_G + base);
        float2 zm = ld2v(ws + OFF_G + 2 * BbHd + base);
        float2 ho = ld2v(ws + OFF_HB + ((t - 1) & 1) * BbHd + base);
        float Z0 = zf.x * zt.x + (1.f - zf.x) * zm.x;
        float Z1 = zf.y * zt.y + (1.f - zf.y) * zm.y;
        float2 hn = make_float2(Z0 * ho.x + (1.f - Z0) * ht0, Z1 * ho.y + (1.f - Z1) * ht1);
        st2v(ws + OFF_HB + (t & 1) * BbHd + base, hn);
        *(float2*)&p.out[(brow * Tt + (t - 1)) * Hd + col] = hn;
        if (t == Tt) *(float2*)&p.out[Bb * Tt * Hd + brow * Hd + col] = hn;
      }
    } else if (j < 56) {   // Ah(t+1): reads XB[(t+1)&1] -> AH[(t+1)&1]
      if (t < Tt) {
        const int jj = j - 48, n0 = jj * 64;
        float2 s = job8<JXB, 256, 256, 64, 4>(p, sm, t, nullptr, 0, rb, n0, p.Wxh, Hd, p.Wxh, Hd);
        const int r = e >> 6, c = e & 63, col = n0 + c;
        st2v(ws + OFF_AH + ((t + 1) & 1) * BbHd + (rb + r) * Hd + col, s);
      }
    } else {               // X-mix(t+2): rows t+1 -> XB[(t+2)&1]
      if (t + 1 < Tt) {
        const int jj = j - 56, n0 = jj * 32;
        const int tp = t + 1;
        float2 s = job8<JX, 512, 256, 32, 4>(p, sm, tp, nullptr, 0, rb, n0, p.fWxt, Ii, p.fWxm, Ii);
        if (tid < 128) {
          const int r = e >> 5, c = e & 31, col = n0 + c, brow = rb + r;
          float2 bv = *(const float2*)&p.fxb[col];
          float g0 = sig1(s.x + bv.x), g1 = sig1(s.y + bv.y);
          float2 xt = *(const float2*)&p.tt[(brow * Tt + tp) * Ii + col];
          float2 xm = *(const float2*)&p.mark[(brow * Tt + tp) * Ii + col];
          st2v(ws + OFF_XB + ((tp + 1) & 1) * BbIi + brow * Ii + col,
               make_float2(g0 * xt.x + (1.f - g0) * xm.x, g1 * xt.y + (1.f - g1) * xm.y));
        }
      }
    }
    grpbar(ws, g, j, ++bt);
  }
}

extern "C" void kernel_launch(void* const* d_in, const int* in_sizes, int n_in,
                              void* d_out, int out_size, void* d_ws, size_t ws_size,
                              hipStream_t stream) {
  P pr;
  pr.tt    = (const float*)d_in[0];
  pr.mark  = (const float*)d_in[1];
  pr.Wxz_t = (const float*)d_in[2];
  pr.Wxr_t = (const float*)d_in[3];
  pr.Wxz_m = (const float*)d_in[4];
  pr.Wxr_m = (const float*)d_in[5];
  pr.Wxh   = (const float*)d_in[6];
  pr.Whz_t = (const float*)d_in[7];
  pr.Whr_t = (const float*)d_in[8];
  pr.Whz_m = (const float*)d_in[9];
  pr.Whr_m = (const float*)d_in[10];
  pr.Whh   = (const float*)d_in[11];
  pr.bz_t  = (const float*)d_in[12];
  pr.br_t  = (const float*)d_in[13];
  pr.bz_m  = (const float*)d_in[14];
  pr.br_m  = (const float*)d_in[15];
  pr.bh    = (const float*)d_in[16];
  pr.fWrt  = (const float*)d_in[17];
  pr.fWrm  = (const float*)d_in[18];
  pr.fWzt  = (const float*)d_in[19];
  pr.fWzm  = (const float*)d_in[20];
  pr.fWxt  = (const float*)d_in[21];
  pr.fWxm  = (const float*)d_in[22];
  pr.frb   = (const float*)d_in[23];
  pr.fzb   = (const float*)d_in[24];
  pr.fxb   = (const float*)d_in[25];
  pr.out = (float*)d_out;
  pr.ws  = (float*)d_ws;

  hipLaunchKernelGGL(ggru_init, dim3(192), dim3(256), 0, stream, (float*)d_ws);

  void* args[] = { (void*)&pr };
  hipError_t err = hipLaunchCooperativeKernel((const void*)ggru_persist,
                                              dim3(NWG), dim3(NTHR),
                                              args, (unsigned)SMEM_BYTES, stream);
  if (err != hipSuccess) {
    hipLaunchKernelGGL(ggru_persist, dim3(NWG), dim3(NTHR), SMEM_BYTES, stream, pr);
  }
}